// Round 11
// baseline (112.537 us; speedup 1.0000x reference)
//
#include <hip/hip_runtime.h>

// Block-resident-LDS fused kernel, 2-n-per-wave weight-fragment sharing.
// R4 b128 LDS layout (0 conflicts), 512-thr blocks, 1 block/CU, grid=256.
// out[n,k,c] = sigmoid(s[n,256+c]) * sum_pq F[pq,k]*(T@X1)[pq,c]*(T@X2)[pq,c]
//              + (k==0 ? silu(s[n,c])*s[n,128+c] : 0)

#define KC    49
#define PQ    324
#define NPX   12544     // 49*256
#define OUTK  6272      // 49*128
#define NTILE 11
// tiled+padded weights in d_ws, staged whole into LDS per block (R4 layout):
// Tw: [11 tiles][32 pq][72 i]  bf16 (144 B rows, 16B-aligned, measured 0-conflict)
// Fw: [11 tiles][64 k ][40 pq] bf16 (80 B rows, 16B-aligned)
#define TWROW  72
#define TWTILE 2304     // 32*72
#define TWTOT  25344    // 11*TWTILE
#define FWROW  40
#define FWTILE 2560     // 64*40
#define FWTOT  28160    // 11*FWTILE
#define WTOT   (TWTOT + FWTOT)   // 53504 elems = 107008 B

typedef __attribute__((ext_vector_type(8)))  short bf16x8;
typedef __attribute__((ext_vector_type(16))) float f32x16;
typedef __attribute__((ext_vector_type(4)))  unsigned int u32x4;

__device__ __forceinline__ unsigned int cvtpk_bf16(float lo, float hi) {
    unsigned int r;
    asm("v_cvt_pk_bf16_f32 %0, %1, %2" : "=v"(r) : "v"(lo), "v"(hi));
    return r;
}
__device__ __forceinline__ unsigned short f2bf(float f) {
    unsigned u = __builtin_bit_cast(unsigned, f);
    return (unsigned short)((u + 0x7FFFu + ((u >> 16) & 1u)) >> 16);   // RNE
}
// 8-dword strided X chunk load (i-rows 16*st+8*hb .. +7, one column)
__device__ __forceinline__ void load_ch(const float* xp, int xi, int st, int hb, float* buf) {
#pragma unroll
    for (int j = 0; j < 8; ++j) {
        const int i = 16 * st + 8 * hb + j;
        buf[j] = (i < KC) ? xp[128 * xi + (size_t)i * 256] : 0.0f;
    }
}
__device__ __forceinline__ bf16x8 cvt_ch(const float* buf) {
    u32x4 d;
#pragma unroll
    for (int p = 0; p < 4; ++p) d[p] = cvtpk_bf16(buf[2 * p], buf[2 * p + 1]);
    return __builtin_bit_cast(bf16x8, d);
}

__global__ void prep_kernel(const float* __restrict__ Tg, const float* __restrict__ Fg,
                            unsigned short* __restrict__ W)
{
    const int idx = blockIdx.x * 256 + threadIdx.x;
    if (idx < TWTOT) {
        const int t = idx / TWTILE, rem = idx % TWTILE;
        const int r = rem / TWROW,  i   = rem % TWROW;
        const int pq = 32 * t + r;
        const float v = (i < KC && pq < PQ) ? Tg[pq * KC + i] : 0.0f;
        W[idx] = f2bf(v);
    } else if (idx < WTOT) {
        const int idx2 = idx - TWTOT;
        const int t = idx2 / FWTILE, rem = idx2 % FWTILE;
        const int k = rem / FWROW,   p   = rem % FWROW;
        const int pq = 32 * t + p;
        const float v = (k < KC && p < 32 && pq < PQ) ? Fg[pq * KC + k] : 0.0f;
        W[idx] = f2bf(v);
    }
}

__global__ __launch_bounds__(512, 2)
void s2_fused(const float* __restrict__ X,            // [N][49][256]
              const float* __restrict__ S,            // [N][384]
              const unsigned short* __restrict__ W,   // tiled Tw+Fw blob
              float* __restrict__ out,                // [N][49][128]
              int nit)                                // iterations (4 n each)
{
    __shared__ __align__(16) unsigned short lds[WTOT];   // 107008 B -> 1 block/CU

    const int tid = threadIdx.x;
    // ---- one-time stage of tiled T/F into LDS ----
    for (int idx = tid; idx < WTOT / 8; idx += 512) {
        const u32x4 v = *(const u32x4*)(W + (size_t)idx * 8);
        *(u32x4*)(lds + (size_t)idx * 8) = v;
    }
    __syncthreads();   // only barrier; LDS read-only afterwards

    const int w  = tid >> 6;
    const int l  = tid & 63;
    const int cl = l & 31;
    const int hb = l >> 5;
    const int cs = w >> 1;   // c-slice 0..3 (c = 32*cs + cl)
    const int nw = w & 1;    // n-lane 0..1

    const unsigned short* tw = lds;
    const unsigned short* fw = lds + TWTOT;

    for (int it = 0; it < nit; ++it) {
        const int base = blockIdx.x * (4 * nit) + 4 * it;
        const int n0 = base + nw;        // this wave's first n
        const int n1 = base + 2 + nw;    // this wave's second n

        // ---- scalars for both n ----
        const float* sp0 = S + (size_t)n0 * 384 + 32 * cs + cl;
        const float* sp1 = S + (size_t)n1 * 384 + 32 * cs + cl;
        const float sg0  = 1.0f / (1.0f + __expf(-sp0[256]));
        const float osc0 = (sp0[0] / (1.0f + __expf(-sp0[0]))) * sp0[128];
        const float sg1  = 1.0f / (1.0f + __expf(-sp1[256]));
        const float osc1 = (sp1[0] / (1.0f + __expf(-sp1[0]))) * sp1[128];

        // ---- X gather for both n: 8-dword chunks, 2-deep rA/rB pipeline ----
        bf16x8 bx0[2][4], bx1[2][4];
        {
            const float* xp0 = X + (size_t)n0 * NPX + 32 * cs + cl;
            float rA[8], rB[8];
            load_ch(xp0, 0, 0, hb, rA);
            load_ch(xp0, 1, 0, hb, rB);
            bx0[0][0] = cvt_ch(rA); load_ch(xp0, 0, 1, hb, rA);
            bx0[1][0] = cvt_ch(rB); load_ch(xp0, 1, 1, hb, rB);
            bx0[0][1] = cvt_ch(rA); load_ch(xp0, 0, 2, hb, rA);
            bx0[1][1] = cvt_ch(rB); load_ch(xp0, 1, 2, hb, rB);
            bx0[0][2] = cvt_ch(rA); load_ch(xp0, 0, 3, hb, rA);
            bx0[1][2] = cvt_ch(rB); load_ch(xp0, 1, 3, hb, rB);
            bx0[0][3] = cvt_ch(rA);
            bx0[1][3] = cvt_ch(rB);
        }
        {
            const float* xp1 = X + (size_t)n1 * NPX + 32 * cs + cl;
            float rA[8], rB[8];
            load_ch(xp1, 0, 0, hb, rA);
            load_ch(xp1, 1, 0, hb, rB);
            bx1[0][0] = cvt_ch(rA); load_ch(xp1, 0, 1, hb, rA);
            bx1[1][0] = cvt_ch(rB); load_ch(xp1, 1, 1, hb, rB);
            bx1[0][1] = cvt_ch(rA); load_ch(xp1, 0, 2, hb, rA);
            bx1[1][1] = cvt_ch(rB); load_ch(xp1, 1, 2, hb, rB);
            bx1[0][2] = cvt_ch(rA); load_ch(xp1, 0, 3, hb, rA);
            bx1[1][2] = cvt_ch(rB); load_ch(xp1, 1, 3, hb, rB);
            bx1[0][3] = cvt_ch(rA);
            bx1[1][3] = cvt_ch(rB);
        }

        f32x16 accO00, accO01, accO10, accO11;
#pragma unroll
        for (int r = 0; r < 16; ++r) {
            accO00[r] = 0.0f; accO01[r] = 0.0f;
            accO10[r] = 0.0f; accO11[r] = 0.0f;
        }

        for (int t = 0; t < NTILE; ++t) {
            // weight frags from LDS once per tile, shared by both n (b128, 0-conflict)
            const unsigned short* twt = tw + t * TWTILE + cl * TWROW + hb * 8;
            const bf16x8 ta0 = *(const bf16x8*)(twt);
            const bf16x8 ta1 = *(const bf16x8*)(twt + 16);
            const bf16x8 ta2 = *(const bf16x8*)(twt + 32);
            const bf16x8 ta3 = *(const bf16x8*)(twt + 48);
            const unsigned short* fwt = fw + t * FWTILE + cl * FWROW + hb * 8;
            const bf16x8 fa00 = *(const bf16x8*)(fwt);
            const bf16x8 fa01 = *(const bf16x8*)(fwt + 16);
            const bf16x8 fa10 = *(const bf16x8*)(fwt + 32 * FWROW);
            const bf16x8 fa11 = *(const bf16x8*)(fwt + 32 * FWROW + 16);

#pragma unroll
            for (int ni = 0; ni < 2; ++ni) {
                const bf16x8 (*bx)[4] = ni ? bx1 : bx0;

                // GEMM1: 32pq x 32c, K=64 in 4 steps, both halves x1/x2
                f32x16 ac0, ac1;
#pragma unroll
                for (int r = 0; r < 16; ++r) { ac0[r] = 0.0f; ac1[r] = 0.0f; }
                ac0 = __builtin_amdgcn_mfma_f32_32x32x16_bf16(ta0, bx[0][0], ac0, 0, 0, 0);
                ac1 = __builtin_amdgcn_mfma_f32_32x32x16_bf16(ta0, bx[1][0], ac1, 0, 0, 0);
                ac0 = __builtin_amdgcn_mfma_f32_32x32x16_bf16(ta1, bx[0][1], ac0, 0, 0, 0);
                ac1 = __builtin_amdgcn_mfma_f32_32x32x16_bf16(ta1, bx[1][1], ac1, 0, 0, 0);
                ac0 = __builtin_amdgcn_mfma_f32_32x32x16_bf16(ta2, bx[0][2], ac0, 0, 0, 0);
                ac1 = __builtin_amdgcn_mfma_f32_32x32x16_bf16(ta2, bx[1][2], ac1, 0, 0, 0);
                ac0 = __builtin_amdgcn_mfma_f32_32x32x16_bf16(ta3, bx[0][3], ac0, 0, 0, 0);
                ac1 = __builtin_amdgcn_mfma_f32_32x32x16_bf16(ta3, bx[1][3], ac1, 0, 0, 0);

                // gate + pack to bf16 pairs
                unsigned int q0 = cvtpk_bf16(ac0[0]  * ac1[0],  ac0[1]  * ac1[1]);
                unsigned int q1 = cvtpk_bf16(ac0[2]  * ac1[2],  ac0[3]  * ac1[3]);
                unsigned int q2 = cvtpk_bf16(ac0[4]  * ac1[4],  ac0[5]  * ac1[5]);
                unsigned int q3 = cvtpk_bf16(ac0[6]  * ac1[6],  ac0[7]  * ac1[7]);
                unsigned int q4 = cvtpk_bf16(ac0[8]  * ac1[8],  ac0[9]  * ac1[9]);
                unsigned int q5 = cvtpk_bf16(ac0[10] * ac1[10], ac0[11] * ac1[11]);
                unsigned int q6 = cvtpk_bf16(ac0[12] * ac1[12], ac0[13] * ac1[13]);
                unsigned int q7 = cvtpk_bf16(ac0[14] * ac1[14], ac0[15] * ac1[15]);

                // half-wave exchange: C-layout (4-row groups) -> B-frag layout (8-row groups)
                asm("v_permlane32_swap_b32 %0, %1" : "+v"(q0), "+v"(q2));
                asm("v_permlane32_swap_b32 %0, %1" : "+v"(q1), "+v"(q3));
                asm("v_permlane32_swap_b32 %0, %1" : "+v"(q4), "+v"(q6));
                asm("v_permlane32_swap_b32 %0, %1" : "+v"(q5), "+v"(q7));
                u32x4 b0v, b1v;
                b0v[0] = q0; b0v[1] = q1; b0v[2] = q2; b0v[3] = q3;
                b1v[0] = q4; b1v[1] = q5; b1v[2] = q6; b1v[3] = q7;
                const bf16x8 bg0 = __builtin_bit_cast(bf16x8, b0v);
                const bf16x8 bg1 = __builtin_bit_cast(bf16x8, b1v);

                // GEMM2: out-tiles k 0..31 / 32..63, two K=16 pq-steps
                if (ni == 0) {
                    accO00 = __builtin_amdgcn_mfma_f32_32x32x16_bf16(fa00, bg0, accO00, 0, 0, 0);
                    accO01 = __builtin_amdgcn_mfma_f32_32x32x16_bf16(fa10, bg0, accO01, 0, 0, 0);
                    accO00 = __builtin_amdgcn_mfma_f32_32x32x16_bf16(fa01, bg1, accO00, 0, 0, 0);
                    accO01 = __builtin_amdgcn_mfma_f32_32x32x16_bf16(fa11, bg1, accO01, 0, 0, 0);
                } else {
                    accO10 = __builtin_amdgcn_mfma_f32_32x32x16_bf16(fa00, bg0, accO10, 0, 0, 0);
                    accO11 = __builtin_amdgcn_mfma_f32_32x32x16_bf16(fa10, bg0, accO11, 0, 0, 0);
                    accO10 = __builtin_amdgcn_mfma_f32_32x32x16_bf16(fa01, bg1, accO10, 0, 0, 0);
                    accO11 = __builtin_amdgcn_mfma_f32_32x32x16_bf16(fa11, bg1, accO11, 0, 0, 0);
                }
            }
        }

        // ---- epilogue: gate, SwiGLU merge at k==0, store both n ----
        {
            float* op = out + (size_t)n0 * OUTK + 32 * cs + cl;
#pragma unroll
            for (int r = 0; r < 16; ++r) {
                const int k0 = (r & 3) + 8 * (r >> 2) + 4 * hb;
                float v = sg0 * accO00[r];
                if (k0 == 0) v += osc0;          // only r==0, hb==0
                op[(size_t)k0 * 128] = v;
                const int k1 = 32 + k0;
                if (k1 < KC) op[(size_t)k1 * 128] = sg0 * accO01[r];
            }
        }
        {
            float* op = out + (size_t)n1 * OUTK + 32 * cs + cl;
#pragma unroll
            for (int r = 0; r < 16; ++r) {
                const int k0 = (r & 3) + 8 * (r >> 2) + 4 * hb;
                float v = sg1 * accO10[r];
                if (k0 == 0) v += osc1;
                op[(size_t)k0 * 128] = v;
                const int k1 = 32 + k0;
                if (k1 < KC) op[(size_t)k1 * 128] = sg1 * accO11[r];
            }
        }
    }
}

extern "C" void kernel_launch(void* const* d_in, const int* in_sizes, int n_in,
                              void* d_out, int out_size, void* d_ws, size_t ws_size,
                              hipStream_t stream) {
    const float* inputs  = (const float*)d_in[0];
    const float* scalars = (const float*)d_in[1];
    const float* Tg      = (const float*)d_in[2];
    const float* Fg      = (const float*)d_in[3];
    float* outp          = (float*)d_out;

    unsigned short* W = (unsigned short*)d_ws;   // WTOT elems = 107008 B

    const int N = in_sizes[1] / 384;             // 4096
    hipLaunchKernelGGL(prep_kernel, dim3((WTOT + 255) / 256), dim3(256), 0, stream,
                       Tg, Fg, W);

    const int nit  = 4;                          // 4 n per iteration
    const int grid = N / (4 * nit);              // 256 blocks = 1/CU, 16 n each
    hipLaunchKernelGGL(s2_fused, dim3(grid), dim3(512), 0, stream,
                       inputs, scalars, W, outp, nit);
}

// Round 12
// 95.211 us; speedup vs baseline: 1.1820x; 1.1820x over previous
//
#include <hip/hip_runtime.h>

// Block-resident-LDS fused kernel. R9 base (64V+64A, 2 blocks/CU, 16 waves/CU)
// + SALU-only per-wave tile-phase rotation (phase decorrelation, zero V delta).
// out[n,k,c] = sigmoid(s[n,256+c]) * sum_pq F[pq,k]*(T@X1)[pq,c]*(T@X2)[pq,c]
//              + (k==0 ? silu(s[n,c])*s[n,128+c] : 0)

#define KC    49
#define PQ    324
#define NPX   12544     // 49*256
#define OUTK  6272      // 49*128
#define NTILE 11
// LDS-resident weights (bf16):
// T[325][68]: row=pq (324 = zero row), col=i (49..67 zero). 136 B rows, b64-aligned.
// F[50][356]: row=k  (49  = zero row), col=pq (324..355 zero). 712 B rows, b64-aligned.
#define TROWS 325
#define TCOLS 68
#define FROWS 50
#define FCOLS 356
#define TTOT  (TROWS * TCOLS)        // 22100
#define FTOT  (FROWS * FCOLS)        // 17800
#define WTOT  (TTOT + FTOT)          // 39900 elems
#define WPAD  39904                  // x8 multiple for 16B staging; 79808 B

typedef __attribute__((ext_vector_type(8)))  short bf16x8;
typedef __attribute__((ext_vector_type(4)))  short bf16x4;
typedef __attribute__((ext_vector_type(16))) float f32x16;
typedef __attribute__((ext_vector_type(4)))  unsigned int u32x4;

__device__ __forceinline__ unsigned int cvtpk_bf16(float lo, float hi) {
    unsigned int r;
    asm("v_cvt_pk_bf16_f32 %0, %1, %2" : "=v"(r) : "v"(lo), "v"(hi));
    return r;
}
__device__ __forceinline__ unsigned short f2bf(float f) {
    unsigned u = __builtin_bit_cast(unsigned, f);
    return (unsigned short)((u + 0x7FFFu + ((u >> 16) & 1u)) >> 16);   // RNE
}
// two ds_read_b64 (rows are only 8-B aligned)
__device__ __forceinline__ bf16x8 ld8(const unsigned short* p) {
    const bf16x4 lo = *(const bf16x4*)p;
    const bf16x4 hi = *(const bf16x4*)(p + 4);
    bf16x8 r;
    r[0] = lo[0]; r[1] = lo[1]; r[2] = lo[2]; r[3] = lo[3];
    r[4] = hi[0]; r[5] = hi[1]; r[6] = hi[2]; r[7] = hi[3];
    return r;
}
// 8-dword strided X chunk load (i-rows 16*st+8*hb .. +7, one column)
__device__ __forceinline__ void load_ch(const float* xp, int xi, int st, int hb, float* buf) {
#pragma unroll
    for (int j = 0; j < 8; ++j) {
        const int i = 16 * st + 8 * hb + j;
        buf[j] = (i < KC) ? xp[128 * xi + (size_t)i * 256] : 0.0f;
    }
}
__device__ __forceinline__ bf16x8 cvt_ch(const float* buf) {
    u32x4 d;
#pragma unroll
    for (int p = 0; p < 4; ++p) d[p] = cvtpk_bf16(buf[2 * p], buf[2 * p + 1]);
    return __builtin_bit_cast(bf16x8, d);
}

__global__ void prep_kernel(const float* __restrict__ Tg, const float* __restrict__ Fg,
                            unsigned short* __restrict__ W)
{
    const int idx = blockIdx.x * 256 + threadIdx.x;
    if (idx < TTOT) {
        const int r = idx / TCOLS, i = idx % TCOLS;
        const float v = (r < PQ && i < KC) ? Tg[r * KC + i] : 0.0f;
        W[idx] = f2bf(v);
    } else if (idx < WPAD) {
        float v = 0.0f;
        if (idx < WTOT) {
            const int idx2 = idx - TTOT;
            const int k = idx2 / FCOLS, p = idx2 % FCOLS;
            if (k < KC && p < PQ) v = Fg[p * KC + k];
        }
        W[idx] = f2bf(v);
    }
}

__global__ __launch_bounds__(512, 4)   // 4 waves/EU: 64V (+64A) per wave -> 2 blocks/CU
void s2_fused(const float* __restrict__ X,            // [N][49][256]
              const float* __restrict__ S,            // [N][384]
              const unsigned short* __restrict__ W,   // T/F blob
              float* __restrict__ out,                // [N][49][128]
              int nit)                                // n-pairs per block
{
    __shared__ __align__(16) unsigned short lds[WPAD];   // 79808 B

    const int tid = threadIdx.x;
    // ---- one-time stage of T/F into LDS ----
    for (int idx = tid; idx < WPAD / 8; idx += 512) {
        const u32x4 v = *(const u32x4*)(W + (size_t)idx * 8);
        *(u32x4*)(lds + (size_t)idx * 8) = v;
    }
    __syncthreads();   // only barrier; LDS read-only afterwards

    const int w  = tid >> 6;
    const int l  = tid & 63;
    const int cl = l & 31;
    const int hb = l >> 5;
    const int cs = w >> 1;   // c-slice 0..3 (c = 32*cs + cl)
    const int nw = w & 1;    // which n of the pair

    const unsigned short* tw  = lds;
    const unsigned short* fw0 = lds + TTOT + (size_t)cl * FCOLS;                 // k = cl
    const unsigned short* fw1 = lds + TTOT + (size_t)min(cl + 32, KC) * FCOLS;   // k = 32+cl (clamp -> zero row)

    // wave-uniform phase rotation state (SALU only; zero per-lane registers)
    int ttc = (3 * w + (int)blockIdx.x) % NTILE;   // this wave's starting tile

    const int nbase = blockIdx.x * (2 * nit) + nw;

    for (int it = 0; it < nit; ++it) {
        const int n = nbase + 2 * it;

        const float* xp = X + (size_t)n * NPX + 32 * cs + cl;
        const float* sp = S + (size_t)n * 384 + 32 * cs + cl;
        const float sraw0 = sp[0], sraw1 = sp[128], sraw2 = sp[256];
        const float sg  = 1.0f / (1.0f + __expf(-sraw2));
        const float osc = (sraw0 / (1.0f + __expf(-sraw0))) * sraw1;

        // ---- X gather: 8 chunks x 8 dwords, explicit 2-deep rA/rB pipeline ----
        bf16x8 bx[2][4];
        {
            float rA[8], rB[8];
            load_ch(xp, 0, 0, hb, rA);
            load_ch(xp, 1, 0, hb, rB);
            bx[0][0] = cvt_ch(rA); load_ch(xp, 0, 1, hb, rA);
            bx[1][0] = cvt_ch(rB); load_ch(xp, 1, 1, hb, rB);
            bx[0][1] = cvt_ch(rA); load_ch(xp, 0, 2, hb, rA);
            bx[1][1] = cvt_ch(rB); load_ch(xp, 1, 2, hb, rB);
            bx[0][2] = cvt_ch(rA); load_ch(xp, 0, 3, hb, rA);
            bx[1][2] = cvt_ch(rB); load_ch(xp, 1, 3, hb, rB);
            bx[0][3] = cvt_ch(rA);
            bx[1][3] = cvt_ch(rB);
        }

        f32x16 accO0, accO1;
#pragma unroll
        for (int r = 0; r < 16; ++r) { accO0[r] = 0.0f; accO1[r] = 0.0f; }

        for (int t = 0; t < NTILE; ++t) {
            const int tbase = 32 * ttc;                          // wave-uniform (SALU)

            const int trow = min(tbase + cl, 324);               // clamp only bites at tile 10
            const unsigned short* twt = tw + trow * TCOLS + 8 * hb;

            f32x16 ac0, ac1;
#pragma unroll
            for (int r = 0; r < 16; ++r) { ac0[r] = 0.0f; ac1[r] = 0.0f; }

            // GEMM1: K=64 in 4 steps; load 2 T-frags at a time (8 V live)
            {
                const bf16x8 ta0 = ld8(twt);
                const bf16x8 ta1 = ld8(twt + 16);
                ac0 = __builtin_amdgcn_mfma_f32_32x32x16_bf16(ta0, bx[0][0], ac0, 0, 0, 0);
                ac1 = __builtin_amdgcn_mfma_f32_32x32x16_bf16(ta0, bx[1][0], ac1, 0, 0, 0);
                ac0 = __builtin_amdgcn_mfma_f32_32x32x16_bf16(ta1, bx[0][1], ac0, 0, 0, 0);
                ac1 = __builtin_amdgcn_mfma_f32_32x32x16_bf16(ta1, bx[1][1], ac1, 0, 0, 0);
            }
            {
                const bf16x8 ta2 = ld8(twt + 32);
                const bf16x8 ta3 = ld8(twt + 48);
                ac0 = __builtin_amdgcn_mfma_f32_32x32x16_bf16(ta2, bx[0][2], ac0, 0, 0, 0);
                ac1 = __builtin_amdgcn_mfma_f32_32x32x16_bf16(ta2, bx[1][2], ac1, 0, 0, 0);
                ac0 = __builtin_amdgcn_mfma_f32_32x32x16_bf16(ta3, bx[0][3], ac0, 0, 0, 0);
                ac1 = __builtin_amdgcn_mfma_f32_32x32x16_bf16(ta3, bx[1][3], ac1, 0, 0, 0);
            }

            // gate + pack to bf16 pairs
            unsigned int q0 = cvtpk_bf16(ac0[0]  * ac1[0],  ac0[1]  * ac1[1]);
            unsigned int q1 = cvtpk_bf16(ac0[2]  * ac1[2],  ac0[3]  * ac1[3]);
            unsigned int q2 = cvtpk_bf16(ac0[4]  * ac1[4],  ac0[5]  * ac1[5]);
            unsigned int q3 = cvtpk_bf16(ac0[6]  * ac1[6],  ac0[7]  * ac1[7]);
            unsigned int q4 = cvtpk_bf16(ac0[8]  * ac1[8],  ac0[9]  * ac1[9]);
            unsigned int q5 = cvtpk_bf16(ac0[10] * ac1[10], ac0[11] * ac1[11]);
            unsigned int q6 = cvtpk_bf16(ac0[12] * ac1[12], ac0[13] * ac1[13]);
            unsigned int q7 = cvtpk_bf16(ac0[14] * ac1[14], ac0[15] * ac1[15]);

            // half-wave exchange: C-layout (4-row groups) -> B-frag layout (8-row groups)
            asm("v_permlane32_swap_b32 %0, %1" : "+v"(q0), "+v"(q2));
            asm("v_permlane32_swap_b32 %0, %1" : "+v"(q1), "+v"(q3));
            asm("v_permlane32_swap_b32 %0, %1" : "+v"(q4), "+v"(q6));
            asm("v_permlane32_swap_b32 %0, %1" : "+v"(q5), "+v"(q7));
            u32x4 b0v, b1v;
            b0v[0] = q0; b0v[1] = q1; b0v[2] = q2; b0v[3] = q3;
            b1v[0] = q4; b1v[1] = q5; b1v[2] = q6; b1v[3] = q7;
            const bf16x8 bg0 = __builtin_bit_cast(bf16x8, b0v);
            const bf16x8 bg1 = __builtin_bit_cast(bf16x8, b1v);

            // GEMM2: 2 F-frags at a time, JIT
            const int fcol = tbase + 8 * hb;
            {
                const bf16x8 fa00 = ld8(fw0 + fcol);
                const bf16x8 fa10 = ld8(fw1 + fcol);
                accO0 = __builtin_amdgcn_mfma_f32_32x32x16_bf16(fa00, bg0, accO0, 0, 0, 0);
                accO1 = __builtin_amdgcn_mfma_f32_32x32x16_bf16(fa10, bg0, accO1, 0, 0, 0);
            }
            {
                const bf16x8 fa01 = ld8(fw0 + fcol + 16);
                const bf16x8 fa11 = ld8(fw1 + fcol + 16);
                accO0 = __builtin_amdgcn_mfma_f32_32x32x16_bf16(fa01, bg1, accO0, 0, 0, 0);
                accO1 = __builtin_amdgcn_mfma_f32_32x32x16_bf16(fa11, bg1, accO1, 0, 0, 0);
            }

            // advance + wrap rotation counter (wave-uniform SALU select)
            ttc = (ttc == NTILE - 1) ? 0 : ttc + 1;
        }

        // ---- epilogue: gate, SwiGLU merge at k==0, store ----
        float* op = out + (size_t)n * OUTK + 32 * cs + cl;
#pragma unroll
        for (int r = 0; r < 16; ++r) {
            const int k0 = (r & 3) + 8 * (r >> 2) + 4 * hb;
            float v = sg * accO0[r];
            if (k0 == 0) v += osc;               // only r==0, hb==0
            op[(size_t)k0 * 128] = v;
            const int k1 = 32 + k0;
            if (k1 < KC) op[(size_t)k1 * 128] = sg * accO1[r];
        }
    }
}

extern "C" void kernel_launch(void* const* d_in, const int* in_sizes, int n_in,
                              void* d_out, int out_size, void* d_ws, size_t ws_size,
                              hipStream_t stream) {
    const float* inputs  = (const float*)d_in[0];
    const float* scalars = (const float*)d_in[1];
    const float* Tg      = (const float*)d_in[2];
    const float* Fg      = (const float*)d_in[3];
    float* outp          = (float*)d_out;

    unsigned short* W = (unsigned short*)d_ws;   // WPAD elems = 79808 B

    const int N = in_sizes[1] / 384;             // 4096
    hipLaunchKernelGGL(prep_kernel, dim3((WPAD + 255) / 256), dim3(256), 0, stream,
                       Tg, Fg, W);

    const int nit  = 4;                          // n-pairs per block
    const int grid = N / (2 * nit);              // 512 blocks -> 2 resident/CU
    hipLaunchKernelGGL(s2_fused, dim3(grid), dim3(512), 0, stream,
                       inputs, scalars, W, outp, nit);
}

// Round 13
// 95.206 us; speedup vs baseline: 1.1820x; 1.0001x over previous
//
#include <hip/hip_runtime.h>

// Block-resident-LDS fused kernel. R12 base + critical-path repair:
// Z-operand MFMA init (no per-tile ac zeroing), next-tile T-frag prefetch,
// early F-frag issue, 4-deep gather pipeline. (512,2) bounds.
// out[n,k,c] = sigmoid(s[n,256+c]) * sum_pq F[pq,k]*(T@X1)[pq,c]*(T@X2)[pq,c]
//              + (k==0 ? silu(s[n,c])*s[n,128+c] : 0)

#define KC    49
#define PQ    324
#define NPX   12544     // 49*256
#define OUTK  6272      // 49*128
#define NTILE 11
// LDS-resident weights (bf16):
// T[325][68]: row=pq (324 = zero row), col=i (49..67 zero). 136 B rows, b64-aligned.
// F[50][356]: row=k  (49  = zero row), col=pq (324..355 zero). 712 B rows, b64-aligned.
#define TROWS 325
#define TCOLS 68
#define FROWS 50
#define FCOLS 356
#define TTOT  (TROWS * TCOLS)        // 22100
#define FTOT  (FROWS * FCOLS)        // 17800
#define WTOT  (TTOT + FTOT)          // 39900 elems
#define WPAD  39904                  // x8 multiple for 16B staging; 79808 B

typedef __attribute__((ext_vector_type(8)))  short bf16x8;
typedef __attribute__((ext_vector_type(4)))  short bf16x4;
typedef __attribute__((ext_vector_type(16))) float f32x16;
typedef __attribute__((ext_vector_type(4)))  unsigned int u32x4;

__device__ __forceinline__ unsigned int cvtpk_bf16(float lo, float hi) {
    unsigned int r;
    asm("v_cvt_pk_bf16_f32 %0, %1, %2" : "=v"(r) : "v"(lo), "v"(hi));
    return r;
}
__device__ __forceinline__ unsigned short f2bf(float f) {
    unsigned u = __builtin_bit_cast(unsigned, f);
    return (unsigned short)((u + 0x7FFFu + ((u >> 16) & 1u)) >> 16);   // RNE
}
// two ds_read_b64 (rows are only 8-B aligned)
__device__ __forceinline__ bf16x8 ld8(const unsigned short* p) {
    const bf16x4 lo = *(const bf16x4*)p;
    const bf16x4 hi = *(const bf16x4*)(p + 4);
    bf16x8 r;
    r[0] = lo[0]; r[1] = lo[1]; r[2] = lo[2]; r[3] = lo[3];
    r[4] = hi[0]; r[5] = hi[1]; r[6] = hi[2]; r[7] = hi[3];
    return r;
}
// 8-dword strided X chunk load (i-rows 16*st+8*hb .. +7, one column)
__device__ __forceinline__ void load_ch(const float* xp, int xi, int st, int hb, float* buf) {
#pragma unroll
    for (int j = 0; j < 8; ++j) {
        const int i = 16 * st + 8 * hb + j;
        buf[j] = (i < KC) ? xp[128 * xi + (size_t)i * 256] : 0.0f;
    }
}
__device__ __forceinline__ bf16x8 cvt_ch(const float* buf) {
    u32x4 d;
#pragma unroll
    for (int p = 0; p < 4; ++p) d[p] = cvtpk_bf16(buf[2 * p], buf[2 * p + 1]);
    return __builtin_bit_cast(bf16x8, d);
}

__global__ void prep_kernel(const float* __restrict__ Tg, const float* __restrict__ Fg,
                            unsigned short* __restrict__ W)
{
    const int idx = blockIdx.x * 256 + threadIdx.x;
    if (idx < TTOT) {
        const int r = idx / TCOLS, i = idx % TCOLS;
        const float v = (r < PQ && i < KC) ? Tg[r * KC + i] : 0.0f;
        W[idx] = f2bf(v);
    } else if (idx < WPAD) {
        float v = 0.0f;
        if (idx < WTOT) {
            const int idx2 = idx - TTOT;
            const int k = idx2 / FCOLS, p = idx2 % FCOLS;
            if (k < KC && p < PQ) v = Fg[p * KC + k];
        }
        W[idx] = f2bf(v);
    }
}

__global__ __launch_bounds__(512, 2)
void s2_fused(const float* __restrict__ X,            // [N][49][256]
              const float* __restrict__ S,            // [N][384]
              const unsigned short* __restrict__ W,   // T/F blob
              float* __restrict__ out,                // [N][49][128]
              int nit,                                // n-pairs per block
              float fzero)                            // 0.0f (opaque to compiler)
{
    __shared__ __align__(16) unsigned short lds[WPAD];   // 79808 B

    const int tid = threadIdx.x;
    // ---- one-time stage of T/F into LDS ----
    for (int idx = tid; idx < WPAD / 8; idx += 512) {
        const u32x4 v = *(const u32x4*)(W + (size_t)idx * 8);
        *(u32x4*)(lds + (size_t)idx * 8) = v;
    }
    __syncthreads();   // only barrier; LDS read-only afterwards

    const int w  = tid >> 6;
    const int l  = tid & 63;
    const int cl = l & 31;
    const int hb = l >> 5;
    const int cs = w >> 1;   // c-slice 0..3 (c = 32*cs + cl)
    const int nw = w & 1;    // which n of the pair

    const unsigned short* tw  = lds;
    const unsigned short* fw0 = lds + TTOT + (size_t)cl * FCOLS;                 // k = cl
    const unsigned short* fw1 = lds + TTOT + (size_t)min(cl + 32, KC) * FCOLS;   // k = 32+cl (clamp -> zero row)

    // opaque zero accumulator (compiler can't fold -> lives in 16 regs, reused as C operand)
    f32x16 Z;
#pragma unroll
    for (int r = 0; r < 16; ++r) Z[r] = fzero;

    // wave-uniform phase rotation (SALU only)
    int ttc = (3 * w + (int)blockIdx.x) % NTILE;

    // initial T-frag prefetch for the first tile
    const unsigned short* twt0 = tw + (size_t)min(32 * ttc + cl, 324) * TCOLS + 8 * hb;
    bf16x8 tc0 = ld8(twt0);
    bf16x8 tc1 = ld8(twt0 + 16);
    bf16x8 tc2 = ld8(twt0 + 32);
    bf16x8 tc3 = ld8(twt0 + 48);

    const int nbase = blockIdx.x * (2 * nit) + nw;

    for (int it = 0; it < nit; ++it) {
        const int n = nbase + 2 * it;

        const float* xp = X + (size_t)n * NPX + 32 * cs + cl;
        const float* sp = S + (size_t)n * 384 + 32 * cs + cl;
        const float sraw0 = sp[0], sraw1 = sp[128], sraw2 = sp[256];
        const float sg  = 1.0f / (1.0f + __expf(-sraw2));
        const float osc = (sraw0 / (1.0f + __expf(-sraw0))) * sraw1;

        // ---- X gather: 16 chunks x 8 dwords, 4-deep pipeline ----
        bf16x8 bx[2][4];
        {
            float r0[8], r1[8], r2[8], r3[8];
            load_ch(xp, 0, 0, hb, r0);
            load_ch(xp, 1, 0, hb, r1);
            load_ch(xp, 0, 1, hb, r2);
            load_ch(xp, 1, 1, hb, r3);
            bx[0][0] = cvt_ch(r0); load_ch(xp, 0, 2, hb, r0);
            bx[1][0] = cvt_ch(r1); load_ch(xp, 1, 2, hb, r1);
            bx[0][1] = cvt_ch(r2); load_ch(xp, 0, 3, hb, r2);
            bx[1][1] = cvt_ch(r3); load_ch(xp, 1, 3, hb, r3);
            bx[0][2] = cvt_ch(r0);
            bx[1][2] = cvt_ch(r1);
            bx[0][3] = cvt_ch(r2);
            bx[1][3] = cvt_ch(r3);
        }

        f32x16 accO0, accO1;
#pragma unroll
        for (int r = 0; r < 16; ++r) { accO0[r] = 0.0f; accO1[r] = 0.0f; }

        for (int t = 0; t < NTILE; ++t) {
            // prefetch NEXT tile's T-frags (used next iteration; latency hidden)
            const int ttn = (ttc == NTILE - 1) ? 0 : ttc + 1;
            const unsigned short* twtN = tw + (size_t)min(32 * ttn + cl, 324) * TCOLS + 8 * hb;
            const bf16x8 nc0 = ld8(twtN);
            const bf16x8 nc1 = ld8(twtN + 16);
            const bf16x8 nc2 = ld8(twtN + 32);
            const bf16x8 nc3 = ld8(twtN + 48);

            // GEMM1: K=64 in 4 steps on prefetched tc*, C-init from opaque Z
            f32x16 ac0, ac1;
            ac0 = __builtin_amdgcn_mfma_f32_32x32x16_bf16(tc0, bx[0][0], Z, 0, 0, 0);
            ac1 = __builtin_amdgcn_mfma_f32_32x32x16_bf16(tc0, bx[1][0], Z, 0, 0, 0);
            ac0 = __builtin_amdgcn_mfma_f32_32x32x16_bf16(tc1, bx[0][1], ac0, 0, 0, 0);
            ac1 = __builtin_amdgcn_mfma_f32_32x32x16_bf16(tc1, bx[1][1], ac1, 0, 0, 0);
            ac0 = __builtin_amdgcn_mfma_f32_32x32x16_bf16(tc2, bx[0][2], ac0, 0, 0, 0);
            ac1 = __builtin_amdgcn_mfma_f32_32x32x16_bf16(tc2, bx[1][2], ac1, 0, 0, 0);
            ac0 = __builtin_amdgcn_mfma_f32_32x32x16_bf16(tc3, bx[0][3], ac0, 0, 0, 0);
            ac1 = __builtin_amdgcn_mfma_f32_32x32x16_bf16(tc3, bx[1][3], ac1, 0, 0, 0);

            // issue F-frags now (latency hides under the pack VALU below)
            const int fcol = 32 * ttc + 8 * hb;
            const bf16x8 fa00 = ld8(fw0 + fcol);
            const bf16x8 fa01 = ld8(fw0 + fcol + 16);
            const bf16x8 fa10 = ld8(fw1 + fcol);
            const bf16x8 fa11 = ld8(fw1 + fcol + 16);

            // gate + pack to bf16 pairs
            unsigned int q0 = cvtpk_bf16(ac0[0]  * ac1[0],  ac0[1]  * ac1[1]);
            unsigned int q1 = cvtpk_bf16(ac0[2]  * ac1[2],  ac0[3]  * ac1[3]);
            unsigned int q2 = cvtpk_bf16(ac0[4]  * ac1[4],  ac0[5]  * ac1[5]);
            unsigned int q3 = cvtpk_bf16(ac0[6]  * ac1[6],  ac0[7]  * ac1[7]);
            unsigned int q4 = cvtpk_bf16(ac0[8]  * ac1[8],  ac0[9]  * ac1[9]);
            unsigned int q5 = cvtpk_bf16(ac0[10] * ac1[10], ac0[11] * ac1[11]);
            unsigned int q6 = cvtpk_bf16(ac0[12] * ac1[12], ac0[13] * ac1[13]);
            unsigned int q7 = cvtpk_bf16(ac0[14] * ac1[14], ac0[15] * ac1[15]);

            // half-wave exchange: C-layout (4-row groups) -> B-frag layout (8-row groups)
            asm("v_permlane32_swap_b32 %0, %1" : "+v"(q0), "+v"(q2));
            asm("v_permlane32_swap_b32 %0, %1" : "+v"(q1), "+v"(q3));
            asm("v_permlane32_swap_b32 %0, %1" : "+v"(q4), "+v"(q6));
            asm("v_permlane32_swap_b32 %0, %1" : "+v"(q5), "+v"(q7));
            u32x4 b0v, b1v;
            b0v[0] = q0; b0v[1] = q1; b0v[2] = q2; b0v[3] = q3;
            b1v[0] = q4; b1v[1] = q5; b1v[2] = q6; b1v[3] = q7;
            const bf16x8 bg0 = __builtin_bit_cast(bf16x8, b0v);
            const bf16x8 bg1 = __builtin_bit_cast(bf16x8, b1v);

            // GEMM2: out-tiles k 0..31 / 32..48
            accO0 = __builtin_amdgcn_mfma_f32_32x32x16_bf16(fa00, bg0, accO0, 0, 0, 0);
            accO1 = __builtin_amdgcn_mfma_f32_32x32x16_bf16(fa10, bg0, accO1, 0, 0, 0);
            accO0 = __builtin_amdgcn_mfma_f32_32x32x16_bf16(fa01, bg1, accO0, 0, 0, 0);
            accO1 = __builtin_amdgcn_mfma_f32_32x32x16_bf16(fa11, bg1, accO1, 0, 0, 0);

            // roll prefetched frags + rotation counter (SALU)
            tc0 = nc0; tc1 = nc1; tc2 = nc2; tc3 = nc3;
            ttc = ttn;
        }
        // after 11 steps ttc wrapped to the start tile, and tc* hold exactly
        // that tile's frags -> prefetch carries across n iterations.

        // ---- epilogue: gate, SwiGLU merge at k==0, store ----
        float* op = out + (size_t)n * OUTK + 32 * cs + cl;
#pragma unroll
        for (int r = 0; r < 16; ++r) {
            const int k0 = (r & 3) + 8 * (r >> 2) + 4 * hb;
            float v = sg * accO0[r];
            if (k0 == 0) v += osc;               // only r==0, hb==0
            op[(size_t)k0 * 128] = v;
            const int k1 = 32 + k0;
            if (k1 < KC) op[(size_t)k1 * 128] = sg * accO1[r];
        }
    }
}

extern "C" void kernel_launch(void* const* d_in, const int* in_sizes, int n_in,
                              void* d_out, int out_size, void* d_ws, size_t ws_size,
                              hipStream_t stream) {
    const float* inputs  = (const float*)d_in[0];
    const float* scalars = (const float*)d_in[1];
    const float* Tg      = (const float*)d_in[2];
    const float* Fg      = (const float*)d_in[3];
    float* outp          = (float*)d_out;

    unsigned short* W = (unsigned short*)d_ws;   // WPAD elems = 79808 B

    const int N = in_sizes[1] / 384;             // 4096
    hipLaunchKernelGGL(prep_kernel, dim3((WPAD + 255) / 256), dim3(256), 0, stream,
                       Tg, Fg, W);

    const int nit  = 4;                          // n-pairs per block
    const int grid = N / (2 * nit);              // 512 blocks
    hipLaunchKernelGGL(s2_fused, dim3(grid), dim3(512), 0, stream,
                       inputs, scalars, W, outp, nit, 0.0f);
}